// Round 3
// baseline (649.955 us; speedup 1.0000x reference)
//
#include <hip/hip_runtime.h>

// GCN 2-layer: N=100000 nodes, E=3200000 edges, F=512, H=16, C=40
// Pipeline:
//   deg[i] = 1 + sum_{e: dst=i} ew[e];  dinv = rsqrt(deg)
//   h  = x @ W1                                  (GEMM1, HBM-bound on x)
//   o1 = h*dinv^2 + scatter(h[s]*dinv[s]*ew*dinv[d])   (prop, atomics)
//   a1 = relu(o1 + b1);  o2init = a1*dinv^2
//   o2 = o2init + scatter(a1[s]*norm)                  (prop, atomics)
//   out = log_softmax(o2 @ W2 + b2)              (W2 applied AFTER prop: associativity)

#define NF 512
#define NH 16

__global__ __launch_bounds__(256) void k_init_deg(float* __restrict__ deg, int n) {
    int i = blockIdx.x * 256 + threadIdx.x;
    if (i < n) deg[i] = 1.0f;   // self-loop weight
}

__global__ __launch_bounds__(256) void k_deg(const int* __restrict__ dst,
                                             const float* __restrict__ ew,
                                             float* __restrict__ deg, int E) {
    int i = blockIdx.x * 256 + threadIdx.x;
    if (i < E) unsafeAtomicAdd(&deg[dst[i]], ew[i]);
}

__global__ __launch_bounds__(256) void k_dinv(float* __restrict__ deg, int n) {
    int i = blockIdx.x * 256 + threadIdx.x;
    if (i < n) deg[i] = rsqrtf(deg[i]);   // deg >= 1 always
}

// h = x @ W1 ; also out1 = h * dinv^2 (self-loop init for prop pass 1).
// One thread per (row, f): wave = 4 rows x 16 f. W1 in LDS, reads are
// 16 distinct addrs x 4-lane broadcast -> conflict-free.
__global__ __launch_bounds__(256) void k_gemm1(const float* __restrict__ x,
                                               const float* __restrict__ w1,
                                               const float* __restrict__ dinv,
                                               float* __restrict__ h,
                                               float* __restrict__ out1, int n) {
    __shared__ float w1s[NF * NH];
    for (int t = threadIdx.x; t < NF * NH; t += 256) w1s[t] = w1[t];
    __syncthreads();
    int tid = blockIdx.x * 256 + threadIdx.x;
    int i = tid >> 4, f = tid & 15;
    if (i >= n) return;
    const float* xr = x + (size_t)i * NF;
    float acc = 0.0f;
#pragma unroll 16
    for (int k = 0; k < NF; ++k) acc = fmaf(xr[k], w1s[k * NH + f], acc);
    float di = dinv[i];
    h[tid] = acc;
    out1[tid] = acc * di * di;
}

// Edge scatter: 16 lanes per edge, one float each.
__global__ __launch_bounds__(256) void k_prop16(const float* __restrict__ hs,
                                                const int* __restrict__ src,
                                                const int* __restrict__ dst,
                                                const float* __restrict__ ew,
                                                const float* __restrict__ dinv,
                                                float* __restrict__ out, int E) {
    int tid = blockIdx.x * 256 + threadIdx.x;
    int e = tid >> 4;
    if (e >= E) return;
    int f = tid & 15;
    int s = src[e], d = dst[e];
    float nrm = dinv[s] * ew[e] * dinv[d];
    unsafeAtomicAdd(&out[d * NH + f], hs[s * NH + f] * nrm);
}

// a1 = relu(o1 + b1) in place; out2 = a1 * dinv^2 (self-loop init for pass 2)
__global__ __launch_bounds__(256) void k_biasrelu(float* __restrict__ o1,
                                                  const float* __restrict__ b1,
                                                  const float* __restrict__ dinv,
                                                  float* __restrict__ o2, int n) {
    int tid = blockIdx.x * 256 + threadIdx.x;
    if (tid >= n * NH) return;
    int i = tid >> 4, f = tid & 15;
    float v = o1[tid] + b1[f];
    v = fmaxf(v, 0.0f);
    float di = dinv[i];
    o1[tid] = v;
    o2[tid] = v * di * di;
}

// out = log_softmax(agg @ W2 + b2), one thread per node, z[40] in registers.
__global__ __launch_bounds__(256) void k_out(const float* __restrict__ agg,
                                             const float* __restrict__ w2,
                                             const float* __restrict__ b2,
                                             float* __restrict__ out, int n) {
    __shared__ float w2s[NH * 40];
    __shared__ float b2s[40];
    for (int t = threadIdx.x; t < NH * 40; t += 256) w2s[t] = w2[t];
    if (threadIdx.x < 40) b2s[threadIdx.x] = b2[threadIdx.x];
    __syncthreads();
    int i = blockIdx.x * 256 + threadIdx.x;
    if (i >= n) return;
    float v[NH];
    const float4* ap = (const float4*)(agg + (size_t)i * NH);
#pragma unroll
    for (int m = 0; m < 4; ++m) {
        float4 t4 = ap[m];
        v[4 * m] = t4.x; v[4 * m + 1] = t4.y; v[4 * m + 2] = t4.z; v[4 * m + 3] = t4.w;
    }
    float z[40];
#pragma unroll
    for (int c = 0; c < 40; ++c) {
        float a = b2s[c];
#pragma unroll
        for (int f = 0; f < NH; ++f) a = fmaf(v[f], w2s[f * 40 + c], a);
        z[c] = a;
    }
    float mx = z[0];
#pragma unroll
    for (int c = 1; c < 40; ++c) mx = fmaxf(mx, z[c]);
    float sum = 0.0f;
#pragma unroll
    for (int c = 0; c < 40; ++c) sum += expf(z[c] - mx);
    float ls = mx + logf(sum);
    float4* op = (float4*)(out + (size_t)i * 40);
#pragma unroll
    for (int m = 0; m < 10; ++m) {
        float4 o;
        o.x = z[4 * m] - ls; o.y = z[4 * m + 1] - ls;
        o.z = z[4 * m + 2] - ls; o.w = z[4 * m + 3] - ls;
        op[m] = o;
    }
}

extern "C" void kernel_launch(void* const* d_in, const int* in_sizes, int n_in,
                              void* d_out, int out_size, void* d_ws, size_t ws_size,
                              hipStream_t stream) {
    const float* x  = (const float*)d_in[0];
    const int*   ei = (const int*)d_in[1];
    const float* ew = (const float*)d_in[2];
    const float* w1 = (const float*)d_in[3];
    const float* b1 = (const float*)d_in[4];
    const float* w2 = (const float*)d_in[5];
    const float* b2 = (const float*)d_in[6];
    float* out = (float*)d_out;

    int n = in_sizes[0] / NF;      // 100000
    int E = in_sizes[2];           // 3200000
    const int* src = ei;
    const int* dst = ei + E;

    float* ws   = (float*)d_ws;
    float* dinv = ws;                      // n floats (deg, then rsqrt in place)
    float* h    = ws + 100000;             // n*16
    float* o1   = ws + 1700000;            // n*16
    float* o2   = ws + 3300000;            // n*16

    int nb_n   = (n + 255) / 256;
    int nb_nf  = (n * NH + 255) / 256;
    int nb_e   = (E + 255) / 256;
    int nb_e16 = (E * 16 + 255) / 256;   // E*16 = 51.2M fits int

    k_init_deg<<<nb_n, 256, 0, stream>>>(dinv, n);
    k_deg<<<nb_e, 256, 0, stream>>>(dst, ew, dinv, E);
    k_dinv<<<nb_n, 256, 0, stream>>>(dinv, n);
    k_gemm1<<<nb_nf, 256, 0, stream>>>(x, w1, dinv, h, o1, n);
    k_prop16<<<nb_e16, 256, 0, stream>>>(h, src, dst, ew, dinv, o1, E);
    k_biasrelu<<<nb_nf, 256, 0, stream>>>(o1, b1, dinv, o2, n);
    k_prop16<<<nb_e16, 256, 0, stream>>>(o1, src, dst, ew, dinv, o2, E);
    k_out<<<nb_n, 256, 0, stream>>>(o2, w2, b2, out, n);
}